// Round 4
// baseline (2835.972 us; speedup 1.0000x reference)
//
#include <hip/hip_runtime.h>
#include <stdint.h>

typedef __attribute__((ext_vector_type(8))) short bf16x8;
typedef __attribute__((ext_vector_type(4))) float f32x4;
typedef __attribute__((ext_vector_type(4))) unsigned short us4;
typedef unsigned short u16;

#define DEVI static __device__ __forceinline__

#define Bb 4
#define Tt 4096
#define Cch 512
#define DFFd 2048
#define Mrows (Bb*Tt)

DEVI u16 f2bf(float f){
  union{float f;unsigned u;} v; v.f = f;
  unsigned r = v.u + 0x7FFFu + ((v.u >> 16) & 1u);
  return (u16)(r >> 16);
}
DEVI float bf2f(u16 h){
  union{unsigned u;float f;} v; v.u = (unsigned)h << 16; return v.f;
}

DEVI void gload16(const void* g, void* l){
  __builtin_amdgcn_global_load_lds((const __attribute__((address_space(1))) unsigned int*)g,
                                   (__attribute__((address_space(3))) unsigned int*)l, 16, 0, 0);
}

// ---------------- split cast f32 -> (hi, lo) bf16 ----------------
__global__ void k_split_cast(const float* __restrict__ in, u16* __restrict__ hi,
                             u16* __restrict__ lo, int n){
  int i = (blockIdx.x * blockDim.x + threadIdx.x) * 4;
  if(i < n){
    float4 f = *(const float4*)(in + i);
    us4 h, l;
    h.x = f2bf(f.x); l.x = f2bf(f.x - bf2f(h.x));
    h.y = f2bf(f.y); l.y = f2bf(f.y - bf2f(h.y));
    h.z = f2bf(f.z); l.z = f2bf(f.z - bf2f(h.z));
    h.w = f2bf(f.w); l.w = f2bf(f.w - bf2f(h.w));
    *(us4*)(hi + i) = h; *(us4*)(lo + i) = l;
  }
}

// ------------- transpose-cast f32 -> bf16 (plain) -------------
__global__ void k_transpose_f32_bf16(const float* __restrict__ in, u16* __restrict__ out,
                                     int inStride, int outStride){
  __shared__ float tile[32][33];
  int c0 = blockIdx.x * 32, r0 = blockIdx.y * 32;
  int tx = threadIdx.x, ty = threadIdx.y; // (32,8)
  #pragma unroll
  for(int j = 0; j < 4; j++)
    tile[ty + 8*j][tx] = in[(size_t)(r0 + ty + 8*j) * inStride + c0 + tx];
  __syncthreads();
  #pragma unroll
  for(int j = 0; j < 4; j++)
    out[(size_t)(c0 + ty + 8*j) * outStride + r0 + tx] = f2bf(tile[tx][ty + 8*j]);
}

// ------------- transpose-cast f32 -> (hi,lo) bf16 -------------
__global__ void k_transpose_split(const float* __restrict__ in, u16* __restrict__ oh,
                                  u16* __restrict__ ol, int inStride, int outStride){
  __shared__ float tile[32][33];
  int c0 = blockIdx.x * 32, r0 = blockIdx.y * 32;
  int tx = threadIdx.x, ty = threadIdx.y;
  #pragma unroll
  for(int j = 0; j < 4; j++)
    tile[ty + 8*j][tx] = in[(size_t)(r0 + ty + 8*j) * inStride + c0 + tx];
  __syncthreads();
  #pragma unroll
  for(int j = 0; j < 4; j++){
    float x = tile[tx][ty + 8*j];
    u16 h = f2bf(x);
    size_t o = (size_t)(c0 + ty + 8*j) * outStride + r0 + tx;
    oh[o] = h; ol[o] = f2bf(x - bf2f(h));
  }
}

// ---------------- split-precision GEMM core ----------------
DEVI void core_split(const u16* __restrict__ Ah, const u16* __restrict__ Al,
                     const u16* __restrict__ Bh, const u16* __restrict__ Bl,
                     int lda, int ldb, int K,
                     u16* Ash, u16* Asl, u16* Bsh, u16* Bsl,
                     f32x4 (&acc)[4][4]){
  const int t = threadIdx.x;
  const int lane = t & 63, w = t >> 6;
  const int l15 = lane & 15, l4 = lane >> 4;
  const int wr = (w >> 1) * 64, wc = (w & 1) * 64;
  for(int kt = 0; kt < K; kt += 32){
    __syncthreads();
    #pragma unroll
    for(int i = 0; i < 2; i++){
      int row = i*64 + (t >> 2);
      int ce  = (t & 3) * 8;
      size_t ao = (size_t)row * lda + kt + ce;
      size_t bo = (size_t)row * ldb + kt + ce;
      gload16(Ah + ao, (char*)Ash + i*4096 + t*16);
      gload16(Al + ao, (char*)Asl + i*4096 + t*16);
      gload16(Bh + bo, (char*)Bsh + i*4096 + t*16);
      gload16(Bl + bo, (char*)Bsl + i*4096 + t*16);
    }
    __syncthreads();
    bf16x8 ah[4], al[4], bh[4], bl[4];
    #pragma unroll
    for(int mi = 0; mi < 4; mi++){
      ah[mi] = *(const bf16x8*)((const char*)Ash + (wr + mi*16 + l15)*64 + l4*16);
      al[mi] = *(const bf16x8*)((const char*)Asl + (wr + mi*16 + l15)*64 + l4*16);
    }
    #pragma unroll
    for(int ni = 0; ni < 4; ni++){
      bh[ni] = *(const bf16x8*)((const char*)Bsh + (wc + ni*16 + l15)*64 + l4*16);
      bl[ni] = *(const bf16x8*)((const char*)Bsl + (wc + ni*16 + l15)*64 + l4*16);
    }
    #pragma unroll
    for(int mi = 0; mi < 4; mi++)
      #pragma unroll
      for(int ni = 0; ni < 4; ni++){
        acc[mi][ni] = __builtin_amdgcn_mfma_f32_16x16x32_bf16(ah[mi], bh[ni], acc[mi][ni], 0, 0, 0);
        acc[mi][ni] = __builtin_amdgcn_mfma_f32_16x16x32_bf16(ah[mi], bl[ni], acc[mi][ni], 0, 0, 0);
        acc[mi][ni] = __builtin_amdgcn_mfma_f32_16x16x32_bf16(al[mi], bh[ni], acc[mi][ni], 0, 0, 0);
      }
  }
}

// ---------------- QK projection, split precision, hi/lo output [M][1024] ----------------
__global__ __launch_bounds__(256) void k_qk_split(const u16* __restrict__ Xh, const u16* __restrict__ Xl,
                                                  const u16* __restrict__ Wh, const u16* __restrict__ Wl,
                                                  u16* __restrict__ Qh, u16* __restrict__ Ql){
  __shared__ u16 Ash[4096], Asl[4096], Bsh[4096], Bsl[4096];
  const int bm = blockIdx.x * 128, bn = blockIdx.y * 128;
  f32x4 acc[4][4] = {};
  core_split(Xh + (size_t)bm*512, Xl + (size_t)bm*512,
             Wh + (size_t)bn*512, Wl + (size_t)bn*512,
             512, 512, 512, Ash, Asl, Bsh, Bsl, acc);
  const int t = threadIdx.x, lane = t & 63, w = t >> 6;
  const int l15 = lane & 15, l4 = lane >> 4;
  const int wr = (w >> 1) * 64, wc = (w & 1) * 64;
  #pragma unroll
  for(int mi = 0; mi < 4; mi++)
    #pragma unroll
    for(int ni = 0; ni < 4; ni++){
      int col = bn + wc + ni*16 + l15;
      #pragma unroll
      for(int r = 0; r < 4; r++){
        int row = bm + wr + mi*16 + l4*4 + r;
        float v = acc[mi][ni][r];
        u16 h = f2bf(v);
        size_t o = (size_t)row * 1024 + col;
        Qh[o] = h; Ql[o] = f2bf(v - bf2f(h));
      }
    }
}

// ---------------- plain GEMM core ----------------
DEVI void core_plain(const u16* __restrict__ A, const u16* __restrict__ B,
                     int lda, int ldb, int K, u16* As, u16* Bs, f32x4 (&acc)[4][4]){
  const int t = threadIdx.x;
  const int lane = t & 63, w = t >> 6;
  const int l15 = lane & 15, l4 = lane >> 4;
  const int wr = (w >> 1) * 64, wc = (w & 1) * 64;
  for(int kt = 0; kt < K; kt += 32){
    __syncthreads();
    #pragma unroll
    for(int i = 0; i < 2; i++){
      int row = i*64 + (t >> 2);
      int ce  = (t & 3) * 8;
      gload16(A + (size_t)row * lda + kt + ce, (char*)As + i*4096 + t*16);
      gload16(B + (size_t)row * ldb + kt + ce, (char*)Bs + i*4096 + t*16);
    }
    __syncthreads();
    bf16x8 af[4], bfr[4];
    #pragma unroll
    for(int mi = 0; mi < 4; mi++)
      af[mi] = *(const bf16x8*)((const char*)As + (wr + mi*16 + l15)*64 + l4*16);
    #pragma unroll
    for(int ni = 0; ni < 4; ni++)
      bfr[ni] = *(const bf16x8*)((const char*)Bs + (wc + ni*16 + l15)*64 + l4*16);
    #pragma unroll
    for(int mi = 0; mi < 4; mi++)
      #pragma unroll
      for(int ni = 0; ni < 4; ni++)
        acc[mi][ni] = __builtin_amdgcn_mfma_f32_16x16x32_bf16(af[mi], bfr[ni], acc[mi][ni], 0, 0, 0);
  }
}

// ---------------- plain GEMM with epilogues ----------------
// EPI: 1 = +bias, relu, store bf16 ; 2 = +bias, store f32 ; 3 = store bf16 blocked-V layout
template<int EPI>
__global__ __launch_bounds__(256) void k_gemm(const u16* __restrict__ A,
                                              const u16* __restrict__ Bt,
                                              void* __restrict__ Cp,
                                              const float* __restrict__ bias,
                                              int K, int ldc){
  __shared__ u16 As[4096], Bs[4096];
  const int bm = blockIdx.x * 128, bn = blockIdx.y * 128;
  f32x4 acc[4][4] = {};
  core_plain(A + (size_t)bm*K, Bt + (size_t)bn*K, K, K, K, As, Bs, acc);
  const int t = threadIdx.x, lane = t & 63, w = t >> 6;
  const int l15 = lane & 15, l4 = lane >> 4;
  const int wr = (w >> 1) * 64, wc = (w & 1) * 64;
  #pragma unroll
  for(int mi = 0; mi < 4; mi++)
    #pragma unroll
    for(int ni = 0; ni < 4; ni++){
      int col = bn + wc + ni*16 + l15;
      float bv = (EPI == 1 || EPI == 2) ? bias[col] : 0.f;
      #pragma unroll
      for(int r = 0; r < 4; r++){
        int row = bm + wr + mi*16 + l4*4 + r;
        float v = acc[mi][ni][r] + bv;
        if(EPI == 1){ v = v > 0.f ? v : 0.f; ((u16*)Cp)[(size_t)row * ldc + col] = f2bf(v); }
        else if(EPI == 2){ ((float*)Cp)[(size_t)row * ldc + col] = v; }
        else {
          // blocked V: Vg[b][t/8][c][t%8]
          int b = row >> 12, tq = row & 4095;
          ((u16*)Cp)[(size_t)b*Cch*Tt + ((size_t)(tq >> 3)*Cch + col)*8 + (tq & 7)] = f2bf(v);
        }
      }
    }
}

// ---------------- Flash attention, split QK^T, swizzled LDS, QB=KVB=32, 2 waves ----------------
__global__ __launch_bounds__(128, 1) void k_attn(const u16* __restrict__ QKh,
                                                 const u16* __restrict__ QKl,
                                                 const u16* __restrict__ Vg,
                                                 u16* __restrict__ NV){
  __shared__ u16 Ksh[32 * 512];     // [kv][c], XOR-swizzled rows   32KB
  __shared__ u16 Ksl[32 * 512];     // 32KB
  __shared__ u16 Vs[4 * 512 * 8];   // [kv/8][c][kv%8] blocked      32KB
  __shared__ u16 Ps[2][16 * 40];

  int bx = blockIdx.x;
  int qt = (bx & 1) ? (127 - (bx >> 1)) : (bx >> 1);  // balance causal work
  int b  = blockIdx.y;
  int t = threadIdx.x, lane = t & 63, w = t >> 6;
  int l15 = lane & 15, l4 = lane >> 4;
  int qbase = qt * 32;
  size_t rowb = (size_t)b * Tt;
  const u16* Vgb = Vg + (size_t)b * Cch * Tt;

  bf16x8 qfh[16], qfl[16];
  {
    const u16* qph = QKh + (rowb + qbase + w*16 + l15) * 1024;
    const u16* qpl = QKl + (rowb + qbase + w*16 + l15) * 1024;
    #pragma unroll
    for(int s = 0; s < 16; s++){
      qfh[s] = *(const bf16x8*)(qph + s*32 + l4*8);
      qfl[s] = *(const bf16x8*)(qpl + s*32 + l4*8);
    }
  }

  f32x4 Ov[32];
  #pragma unroll
  for(int nt = 0; nt < 32; nt++) Ov[nt] = (f32x4){0.f,0.f,0.f,0.f};
  float mrow[4], lrow[4];
  #pragma unroll
  for(int r = 0; r < 4; r++){ mrow[r] = -__builtin_inff(); lrow[r] = 0.f; }

  const int swr = (l15 & 7) << 4;   // read-side XOR for K tiles

  const int ntiles = qt + 1;
  for(int it = 0; it < ntiles; ++it){
    int kv0 = it * 32;
    __syncthreads();
    #pragma unroll
    for(int i = 0; i < 16; i++){
      // K hi/lo: row kv0+i*2+w, source col pre-swizzled (involution with read XOR)
      int kvr = i*2 + w;
      size_t krow = (rowb + kv0 + kvr) * 1024 + 512;
      int coff = (lane*8) ^ ((kvr & 7) << 3);
      gload16(QKh + krow + coff, (char*)Ksh + i*2048 + t*16);
      gload16(QKl + krow + coff, (char*)Ksl + i*2048 + t*16);
      // V: blocked global -> blocked LDS, contiguous source
      const u16* gv = Vgb + (size_t)((kv0 >> 3) + (i >> 2)) * 4096 + ((i & 3)*128 + t)*8;
      gload16(gv, (char*)Vs + i*2048 + t*16);
    }
    __syncthreads();

    // S = Q K^T  split precision (2 column tiles of 16)
    f32x4 sf[2];
    sf[0] = (f32x4){0.f,0.f,0.f,0.f};
    sf[1] = (f32x4){0.f,0.f,0.f,0.f};
    #pragma unroll
    for(int ct = 0; ct < 2; ct++){
      #pragma unroll
      for(int s = 0; s < 16; s++){
        int cb = (s*64 + l4*16) ^ swr;
        bf16x8 kfh = *(const bf16x8*)((const char*)Ksh + (ct*16 + l15)*1024 + cb);
        bf16x8 kfl = *(const bf16x8*)((const char*)Ksl + (ct*16 + l15)*1024 + cb);
        sf[ct] = __builtin_amdgcn_mfma_f32_16x16x32_bf16(qfh[s], kfh, sf[ct], 0, 0, 0);
        sf[ct] = __builtin_amdgcn_mfma_f32_16x16x32_bf16(qfh[s], kfl, sf[ct], 0, 0, 0);
        sf[ct] = __builtin_amdgcn_mfma_f32_16x16x32_bf16(qfl[s], kfh, sf[ct], 0, 0, 0);
      }
    }

    // causal mask + online softmax with defer-max (THR=8)
    int qg = qbase + w*16 + l4*4;
    int kg0 = kv0 + l15, kg1 = kv0 + 16 + l15;
    float s0v[4], s1v[4], tmax[4];
    bool grew = false;
    #pragma unroll
    for(int r = 0; r < 4; r++){
      float s0 = sf[0][r]; if(kg0 > qg + r) s0 = -__builtin_inff();
      float s1 = sf[1][r]; if(kg1 > qg + r) s1 = -__builtin_inff();
      s0v[r] = s0; s1v[r] = s1;
      float tm = fmaxf(s0, s1);
      tm = fmaxf(tm, __shfl_xor(tm, 1));
      tm = fmaxf(tm, __shfl_xor(tm, 2));
      tm = fmaxf(tm, __shfl_xor(tm, 4));
      tm = fmaxf(tm, __shfl_xor(tm, 8));
      tmax[r] = tm;
      if(tm > mrow[r] + 8.f) grew = true;
    }
    if(__any(grew)){
      float scl[4];
      #pragma unroll
      for(int r = 0; r < 4; r++){
        float m2 = fmaxf(mrow[r], tmax[r]);
        scl[r] = __expf(mrow[r] - m2);
        mrow[r] = m2;
        lrow[r] *= scl[r];
      }
      #pragma unroll
      for(int nt = 0; nt < 32; nt++){
        #pragma unroll
        for(int r = 0; r < 4; r++) Ov[nt][r] *= scl[r];
      }
    }
    float p0[4], p1[4];
    #pragma unroll
    for(int r = 0; r < 4; r++){
      p0[r] = __expf(s0v[r] - mrow[r]);
      p1[r] = __expf(s1v[r] - mrow[r]);
      float psum = p0[r] + p1[r];
      psum += __shfl_xor(psum, 1);
      psum += __shfl_xor(psum, 2);
      psum += __shfl_xor(psum, 4);
      psum += __shfl_xor(psum, 8);
      lrow[r] += psum;
    }

    // P -> LDS -> A-operand layout
    u16* Pw = &Ps[w][0];
    #pragma unroll
    for(int r = 0; r < 4; r++){
      Pw[(l4*4 + r)*40 + l15]      = f2bf(p0[r]);
      Pw[(l4*4 + r)*40 + 16 + l15] = f2bf(p1[r]);
    }
    bf16x8 paf = *(const bf16x8*)(Pw + l15*40 + l4*8);

    // O += P V  (Vs blocked: conflict-free)
    #pragma unroll
    for(int nt = 0; nt < 32; nt++){
      bf16x8 vf = *(const bf16x8*)((const char*)Vs + l4*8192 + (nt*16 + l15)*16);
      Ov[nt] = __builtin_amdgcn_mfma_f32_16x16x32_bf16(paf, vf, Ov[nt], 0, 0, 0);
    }
  }

  u16* op = NV + (rowb + qbase + w*16) * Cch;
  #pragma unroll
  for(int nt = 0; nt < 32; nt++){
    #pragma unroll
    for(int r = 0; r < 4; r++){
      float v = Ov[nt][r] / lrow[r];
      op[(size_t)(l4*4 + r) * Cch + nt*16 + l15] = f2bf(v);
    }
  }
}

// ---------------- launch ----------------
extern "C" void kernel_launch(void* const* d_in, const int* in_sizes, int n_in,
                              void* d_out, int out_size, void* d_ws, size_t ws_size,
                              hipStream_t stream){
  (void)in_sizes; (void)n_in; (void)out_size; (void)ws_size;
  const float* X  = (const float*)d_in[0];
  const float* Wq = (const float*)d_in[1];
  const float* Wk = (const float*)d_in[2];
  const float* Wv = (const float*)d_in[3];
  const float* W1 = (const float*)d_in[4];
  const float* b1 = (const float*)d_in[5];
  const float* W2 = (const float*)d_in[6];
  const float* b2 = (const float*)d_in[7];
  float* out = (float*)d_out;

  // workspace layout (byte offsets), total 134.5 MB; H aliases {Xh,Xl,QKl}
  const size_t MB = 1024ull*1024ull;
  char* ws = (char*)d_ws;
  u16* Xh   = (u16*)(ws + 0);        // 16MB, dead after projections
  u16* Xl   = (u16*)(ws + 16*MB);    // 16MB, dead after QK-proj
  u16* QKl  = (u16*)(ws + 32*MB);    // 32MB, dead after attn
  u16* H    = (u16*)(ws + 0);        // 64MB, alias: FFN stage only
  u16* QKh  = (u16*)(ws + 64*MB);    // 32MB
  u16* Vg   = (u16*)(ws + 96*MB);    // 16MB, blocked [b][t/8][c][t%8]
  u16* NV   = (u16*)(ws + 112*MB);   // 16MB
  u16* Wqkh = (u16*)(ws + 128*MB);   // 1MB
  u16* Wqkl = (u16*)(ws + 129*MB);   // 1MB
  u16* Wvt  = (u16*)(ws + 130*MB);   // 0.5MB
  u16* W1t  = (u16*)(ws + 131*MB);   // 2MB
  u16* W2t  = (u16*)(ws + 133*MB);   // 2MB

  dim3 tb(32, 8);

  // 1. split-cast X
  k_split_cast<<<Mrows*Cch/4/256, 256, 0, stream>>>(X, Xh, Xl, Mrows*Cch);

  // 2. weight transposes (Wq/Wk split, Wv/W1/W2 plain)
  k_transpose_split<<<dim3(16,16), tb, 0, stream>>>(Wq, Wqkh,           Wqkl,           512, 512);
  k_transpose_split<<<dim3(16,16), tb, 0, stream>>>(Wk, Wqkh + 512*512, Wqkl + 512*512, 512, 512);
  k_transpose_f32_bf16<<<dim3(16,16), tb, 0, stream>>>(Wv, Wvt, 512, 512);
  k_transpose_f32_bf16<<<dim3(64,16), tb, 0, stream>>>(W1, W1t, 2048, 512);
  k_transpose_f32_bf16<<<dim3(16,64), tb, 0, stream>>>(W2, W2t, 512, 2048);

  // 3. QK projection (split), V projection (plain, writes blocked Vg)
  k_qk_split<<<dim3(128, 8), 256, 0, stream>>>(Xh, Xl, Wqkh, Wqkl, QKh, QKl);
  k_gemm<3><<<dim3(128, 4), 256, 0, stream>>>(Xh, Wvt, Vg, nullptr, Cch, Cch);

  // 4. fused causal flash attention (split QK^T, swizzled LDS)
  k_attn<<<dim3(128, Bb), 128, 0, stream>>>(QKh, QKl, Vg, NV);

  // 5. FFN
  k_gemm<1><<<dim3(128, 16), 256, 0, stream>>>(NV, W1t, H,   b1, Cch,  DFFd);
  k_gemm<2><<<dim3(128, 4),  256, 0, stream>>>(H,  W2t, out, b2, DFFd, Cch);
}

// Round 5
// 628.218 us; speedup vs baseline: 4.5143x; 4.5143x over previous
//
#include <hip/hip_runtime.h>
#include <stdint.h>

typedef __attribute__((ext_vector_type(8))) short bf16x8;
typedef __attribute__((ext_vector_type(4))) float f32x4;
typedef __attribute__((ext_vector_type(4))) unsigned short us4;
typedef unsigned short u16;

#define DEVI static __device__ __forceinline__

#define Bb 4
#define Tt 4096
#define Cch 512
#define DFFd 2048
#define Mrows (Bb*Tt)

DEVI u16 f2bf(float f){
  union{float f;unsigned u;} v; v.f = f;
  unsigned r = v.u + 0x7FFFu + ((v.u >> 16) & 1u);
  return (u16)(r >> 16);
}
DEVI float bf2f(u16 h){
  union{unsigned u;float f;} v; v.u = (unsigned)h << 16; return v.f;
}
// packed-triangular pane offset (f32 elements): sum_{j<q}(j+1)*128*128
DEVI size_t PANE(int q){ return (size_t)8192 * (size_t)(q*(q+1)); }

DEVI void gload16(const void* g, void* l){
  __builtin_amdgcn_global_load_lds((const __attribute__((address_space(1))) unsigned int*)g,
                                   (__attribute__((address_space(3))) unsigned int*)l, 16, 0, 0);
}

// ---------------- split cast f32 -> (hi, lo) bf16 ----------------
__global__ void k_split_cast(const float* __restrict__ in, u16* __restrict__ hi,
                             u16* __restrict__ lo, int n){
  int i = (blockIdx.x * blockDim.x + threadIdx.x) * 4;
  if(i < n){
    float4 f = *(const float4*)(in + i);
    us4 h, l;
    h.x = f2bf(f.x); l.x = f2bf(f.x - bf2f(h.x));
    h.y = f2bf(f.y); l.y = f2bf(f.y - bf2f(h.y));
    h.z = f2bf(f.z); l.z = f2bf(f.z - bf2f(h.z));
    h.w = f2bf(f.w); l.w = f2bf(f.w - bf2f(h.w));
    *(us4*)(hi + i) = h; *(us4*)(lo + i) = l;
  }
}

// ------------- transpose-cast f32 -> bf16 (plain) -------------
__global__ void k_transpose_f32_bf16(const float* __restrict__ in, u16* __restrict__ out,
                                     int inStride, int outStride){
  __shared__ float tile[32][33];
  int c0 = blockIdx.x * 32, r0 = blockIdx.y * 32;
  int tx = threadIdx.x, ty = threadIdx.y; // (32,8)
  #pragma unroll
  for(int j = 0; j < 4; j++)
    tile[ty + 8*j][tx] = in[(size_t)(r0 + ty + 8*j) * inStride + c0 + tx];
  __syncthreads();
  #pragma unroll
  for(int j = 0; j < 4; j++)
    out[(size_t)(c0 + ty + 8*j) * outStride + r0 + tx] = f2bf(tile[tx][ty + 8*j]);
}

// ------------- transpose-cast f32 -> (hi,lo) bf16 -------------
__global__ void k_transpose_split(const float* __restrict__ in, u16* __restrict__ oh,
                                  u16* __restrict__ ol, int inStride, int outStride){
  __shared__ float tile[32][33];
  int c0 = blockIdx.x * 32, r0 = blockIdx.y * 32;
  int tx = threadIdx.x, ty = threadIdx.y;
  #pragma unroll
  for(int j = 0; j < 4; j++)
    tile[ty + 8*j][tx] = in[(size_t)(r0 + ty + 8*j) * inStride + c0 + tx];
  __syncthreads();
  #pragma unroll
  for(int j = 0; j < 4; j++){
    float x = tile[tx][ty + 8*j];
    u16 h = f2bf(x);
    size_t o = (size_t)(c0 + ty + 8*j) * outStride + r0 + tx;
    oh[o] = h; ol[o] = f2bf(x - bf2f(h));
  }
}

// ---------------- split-precision GEMM core ----------------
DEVI void core_split(const u16* __restrict__ Ah, const u16* __restrict__ Al,
                     const u16* __restrict__ Bh, const u16* __restrict__ Bl,
                     int lda, int ldb, int K,
                     u16* Ash, u16* Asl, u16* Bsh, u16* Bsl,
                     f32x4 (&acc)[4][4]){
  const int t = threadIdx.x;
  const int lane = t & 63, w = t >> 6;
  const int l15 = lane & 15, l4 = lane >> 4;
  const int wr = (w >> 1) * 64, wc = (w & 1) * 64;
  for(int kt = 0; kt < K; kt += 32){
    __syncthreads();
    #pragma unroll
    for(int i = 0; i < 2; i++){
      int row = i*64 + (t >> 2);
      int ce  = (t & 3) * 8;
      size_t ao = (size_t)row * lda + kt + ce;
      size_t bo = (size_t)row * ldb + kt + ce;
      gload16(Ah + ao, (char*)Ash + i*4096 + t*16);
      gload16(Al + ao, (char*)Asl + i*4096 + t*16);
      gload16(Bh + bo, (char*)Bsh + i*4096 + t*16);
      gload16(Bl + bo, (char*)Bsl + i*4096 + t*16);
    }
    __syncthreads();
    bf16x8 ah[4], al[4], bh[4], bl[4];
    #pragma unroll
    for(int mi = 0; mi < 4; mi++){
      ah[mi] = *(const bf16x8*)((const char*)Ash + (wr + mi*16 + l15)*64 + l4*16);
      al[mi] = *(const bf16x8*)((const char*)Asl + (wr + mi*16 + l15)*64 + l4*16);
    }
    #pragma unroll
    for(int ni = 0; ni < 4; ni++){
      bh[ni] = *(const bf16x8*)((const char*)Bsh + (wc + ni*16 + l15)*64 + l4*16);
      bl[ni] = *(const bf16x8*)((const char*)Bsl + (wc + ni*16 + l15)*64 + l4*16);
    }
    #pragma unroll
    for(int mi = 0; mi < 4; mi++)
      #pragma unroll
      for(int ni = 0; ni < 4; ni++){
        acc[mi][ni] = __builtin_amdgcn_mfma_f32_16x16x32_bf16(ah[mi], bh[ni], acc[mi][ni], 0, 0, 0);
        acc[mi][ni] = __builtin_amdgcn_mfma_f32_16x16x32_bf16(ah[mi], bl[ni], acc[mi][ni], 0, 0, 0);
        acc[mi][ni] = __builtin_amdgcn_mfma_f32_16x16x32_bf16(al[mi], bh[ni], acc[mi][ni], 0, 0, 0);
      }
  }
}

// ---------------- QK projection, split precision, hi/lo output [M][1024] ----------------
__global__ __launch_bounds__(256) void k_qk_split(const u16* __restrict__ Xh, const u16* __restrict__ Xl,
                                                  const u16* __restrict__ Wh, const u16* __restrict__ Wl,
                                                  u16* __restrict__ Qh, u16* __restrict__ Ql){
  __shared__ u16 Ash[4096], Asl[4096], Bsh[4096], Bsl[4096];
  const int bm = blockIdx.x * 128, bn = blockIdx.y * 128;
  f32x4 acc[4][4] = {};
  core_split(Xh + (size_t)bm*512, Xl + (size_t)bm*512,
             Wh + (size_t)bn*512, Wl + (size_t)bn*512,
             512, 512, 512, Ash, Asl, Bsh, Bsl, acc);
  const int t = threadIdx.x, lane = t & 63, w = t >> 6;
  const int l15 = lane & 15, l4 = lane >> 4;
  const int wr = (w >> 1) * 64, wc = (w & 1) * 64;
  #pragma unroll
  for(int mi = 0; mi < 4; mi++)
    #pragma unroll
    for(int ni = 0; ni < 4; ni++){
      int col = bn + wc + ni*16 + l15;
      #pragma unroll
      for(int r = 0; r < 4; r++){
        int row = bm + wr + mi*16 + l4*4 + r;
        float v = acc[mi][ni][r];
        u16 h = f2bf(v);
        size_t o = (size_t)row * 1024 + col;
        Qh[o] = h; Ql[o] = f2bf(v - bf2f(h));
      }
    }
}

// ---------------- causal score GEMM (one batch), split precision, packed f32 out ----------------
__global__ __launch_bounds__(256) void k_score(const u16* __restrict__ QKhb,
                                               const u16* __restrict__ QKlb,
                                               float* __restrict__ Sp){
  const int kt = blockIdx.x, qt = blockIdx.y;
  if(kt > qt) return;
  __shared__ u16 Ash[4096], Asl[4096], Bsh[4096], Bsl[4096];
  const u16* Ah = QKhb + (size_t)(qt*128) * 1024;
  const u16* Al = QKlb + (size_t)(qt*128) * 1024;
  const u16* Bh = QKhb + (size_t)(kt*128) * 1024 + 512;
  const u16* Bl = QKlb + (size_t)(kt*128) * 1024 + 512;
  f32x4 acc[4][4] = {};
  core_split(Ah, Al, Bh, Bl, 1024, 1024, 512, Ash, Asl, Bsh, Bsl, acc);
  const int t = threadIdx.x, lane = t & 63, w = t >> 6;
  const int l15 = lane & 15, l4 = lane >> 4;
  const int wr = (w >> 1) * 64, wc = (w & 1) * 64;
  const int ldc = (qt + 1) * 128;
  float* C = Sp + PANE(qt) + (size_t)kt*128;
  const bool diag = (kt == qt);
  #pragma unroll
  for(int mi = 0; mi < 4; mi++)
    #pragma unroll
    for(int ni = 0; ni < 4; ni++){
      int cl = wc + ni*16 + l15;
      #pragma unroll
      for(int r = 0; r < 4; r++){
        int rl = wr + mi*16 + l4*4 + r;
        float v = acc[mi][ni][r];
        if(diag && cl > rl) v = -__builtin_inff();
        C[(size_t)rl * ldc + cl] = v;
      }
    }
}

// ---------------- softmax (one batch): wave per row, f32 -> packed bf16 in row's own bytes ----------------
__global__ __launch_bounds__(256) void k_softmax(float* __restrict__ Sp){
  const int w = threadIdx.x >> 6, lane = threadIdx.x & 63;
  const int r = blockIdx.x * 4 + w;           // 0..4095
  const int qt = r >> 7;
  const int L = (qt + 1) * 128, nc = qt + 1;  // chunks of 128 f32 (float2/lane)
  const size_t base = PANE(qt) + (size_t)(r & 127) * L;
  const float2* rp = (const float2*)(Sp + base);
  float2 v[32];
  float mx = -__builtin_inff();
  #pragma unroll
  for(int c = 0; c < 32; c++) if(c < nc){
    v[c] = rp[c*64 + lane];
    mx = fmaxf(mx, fmaxf(v[c].x, v[c].y));
  }
  #pragma unroll
  for(int s = 1; s < 64; s <<= 1) mx = fmaxf(mx, __shfl_xor(mx, s));
  float sm = 0.f;
  #pragma unroll
  for(int c = 0; c < 32; c++) if(c < nc){
    v[c].x = __expf(v[c].x - mx);
    v[c].y = __expf(v[c].y - mx);
    sm += v[c].x + v[c].y;
  }
  #pragma unroll
  for(int s = 1; s < 64; s <<= 1) sm += __shfl_xor(sm, s);
  const float inv = 1.f / sm;
  // bf16 P packed at the START of this row's own f32 region (no cross-row overlap)
  ushort2* wp = (ushort2*)((u16*)Sp + 2*base);
  #pragma unroll
  for(int c = 0; c < 32; c++) if(c < nc){
    ushort2 o; o.x = f2bf(v[c].x * inv); o.y = f2bf(v[c].y * inv);
    wp[c*64 + lane] = o;
  }
}

// ---------------- plain GEMM core ----------------
DEVI void core_plain(const u16* __restrict__ A, const u16* __restrict__ B,
                     int lda, int ldb, int K, u16* As, u16* Bs, f32x4 (&acc)[4][4]){
  const int t = threadIdx.x;
  const int lane = t & 63, w = t >> 6;
  const int l15 = lane & 15, l4 = lane >> 4;
  const int wr = (w >> 1) * 64, wc = (w & 1) * 64;
  for(int kt = 0; kt < K; kt += 32){
    __syncthreads();
    #pragma unroll
    for(int i = 0; i < 2; i++){
      int row = i*64 + (t >> 2);
      int ce  = (t & 3) * 8;
      gload16(A + (size_t)row * lda + kt + ce, (char*)As + i*4096 + t*16);
      gload16(B + (size_t)row * ldb + kt + ce, (char*)Bs + i*4096 + t*16);
    }
    __syncthreads();
    bf16x8 af[4], bfr[4];
    #pragma unroll
    for(int mi = 0; mi < 4; mi++)
      af[mi] = *(const bf16x8*)((const char*)As + (wr + mi*16 + l15)*64 + l4*16);
    #pragma unroll
    for(int ni = 0; ni < 4; ni++)
      bfr[ni] = *(const bf16x8*)((const char*)Bs + (wc + ni*16 + l15)*64 + l4*16);
    #pragma unroll
    for(int mi = 0; mi < 4; mi++)
      #pragma unroll
      for(int ni = 0; ni < 4; ni++)
        acc[mi][ni] = __builtin_amdgcn_mfma_f32_16x16x32_bf16(af[mi], bfr[ni], acc[mi][ni], 0, 0, 0);
  }
}

// ---------------- PV split-K GEMM (one batch): atomicAdd into f32 accumulator ----------------
__global__ __launch_bounds__(256) void k_pv(const u16* __restrict__ Pp, const u16* __restrict__ Vtb,
                                            float* __restrict__ NVacc){
  const int nc = blockIdx.x, qt = blockIdx.y, kc = blockIdx.z;
  const int L = (qt + 1) * 128;
  const int k0 = kc * 1024;
  if(k0 >= L) return;
  const int kLen = (L - k0) < 1024 ? (L - k0) : 1024;
  __shared__ u16 As[4096], Bs[4096];
  const u16* A = Pp + 2*PANE(qt) + k0;                 // P rows: u16 stride 2L, data in low L
  const u16* B = Vtb + (size_t)(nc*128) * Tt + k0;     // Vt rows = V columns
  f32x4 acc[4][4] = {};
  core_plain(A, B, 2*L, Tt, kLen, As, Bs, acc);
  const int t = threadIdx.x, lane = t & 63, w = t >> 6;
  const int l15 = lane & 15, l4 = lane >> 4;
  const int wr = (w >> 1) * 64, wc = (w & 1) * 64;
  float* Cb = NVacc + (size_t)(qt*128) * Cch + nc*128;
  #pragma unroll
  for(int mi = 0; mi < 4; mi++)
    #pragma unroll
    for(int ni = 0; ni < 4; ni++){
      int cl = wc + ni*16 + l15;
      #pragma unroll
      for(int r = 0; r < 4; r++){
        int rl = wr + mi*16 + l4*4 + r;
        atomicAdd(&Cb[(size_t)rl * Cch + cl], acc[mi][ni][r]);
      }
    }
}

// ---------------- plain GEMM with epilogues ----------------
// EPI: 1 = +bias, relu, store bf16 ; 2 = +bias, store f32 ; 4 = store bf16 transposed per batch (Vt)
template<int EPI>
__global__ __launch_bounds__(256) void k_gemm(const u16* __restrict__ A,
                                              const u16* __restrict__ Bt,
                                              void* __restrict__ Cp,
                                              const float* __restrict__ bias,
                                              int K, int ldc){
  __shared__ u16 As[4096], Bs[4096];
  const int bm = blockIdx.x * 128, bn = blockIdx.y * 128;
  f32x4 acc[4][4] = {};
  core_plain(A + (size_t)bm*K, Bt + (size_t)bn*K, K, K, K, As, Bs, acc);
  const int t = threadIdx.x, lane = t & 63, w = t >> 6;
  const int l15 = lane & 15, l4 = lane >> 4;
  const int wr = (w >> 1) * 64, wc = (w & 1) * 64;
  #pragma unroll
  for(int mi = 0; mi < 4; mi++)
    #pragma unroll
    for(int ni = 0; ni < 4; ni++){
      int col = bn + wc + ni*16 + l15;
      float bv = (EPI == 1 || EPI == 2) ? bias[col] : 0.f;
      #pragma unroll
      for(int r = 0; r < 4; r++){
        int row = bm + wr + mi*16 + l4*4 + r;
        float v = acc[mi][ni][r] + bv;
        if(EPI == 1){ v = v > 0.f ? v : 0.f; ((u16*)Cp)[(size_t)row * ldc + col] = f2bf(v); }
        else if(EPI == 2){ ((float*)Cp)[(size_t)row * ldc + col] = v; }
        else {
          // Vt[b][col][t] = V[row][col]
          int b = row >> 12, tq = row & 4095;
          ((u16*)Cp)[((size_t)b * Cch + col) * Tt + tq] = f2bf(v);
        }
      }
    }
}

// ---------------- small utility kernels ----------------
__global__ void k_zero4(float* __restrict__ p, int n){
  int i = (blockIdx.x * blockDim.x + threadIdx.x) * 4;
  if(i < n) *(f32x4*)(p + i) = (f32x4){0.f,0.f,0.f,0.f};
}
__global__ void k_nv_final(const float* __restrict__ acc, u16* __restrict__ nv, int n){
  int i = (blockIdx.x * blockDim.x + threadIdx.x) * 4;
  if(i < n){
    f32x4 v = *(const f32x4*)(acc + i);
    us4 o; o.x = f2bf(v[0]); o.y = f2bf(v[1]); o.z = f2bf(v[2]); o.w = f2bf(v[3]);
    *(us4*)(nv + i) = o;
  }
}

// ---------------- launch ----------------
extern "C" void kernel_launch(void* const* d_in, const int* in_sizes, int n_in,
                              void* d_out, int out_size, void* d_ws, size_t ws_size,
                              hipStream_t stream){
  (void)in_sizes; (void)n_in; (void)out_size; (void)ws_size;
  const float* X  = (const float*)d_in[0];
  const float* Wq = (const float*)d_in[1];
  const float* Wk = (const float*)d_in[2];
  const float* Wv = (const float*)d_in[3];
  const float* W1 = (const float*)d_in[4];
  const float* b1 = (const float*)d_in[5];
  const float* W2 = (const float*)d_in[6];
  const float* b2 = (const float*)d_in[7];
  float* out = (float*)d_out;

  // workspace layout (byte offsets), peak ~169.6 MB
  // 0   Xh(16)  -> later NVacc(8) -> later H(64, spans 0-64)
  // 16  Xl(16)
  // 32  QKl(32)    dead after last k_score
  // 64  QKh(32)    dead after last k_score
  // 96  Vt(16)
  // 112 NV(16)
  // 128 weights (7)
  // 135 S pane buffer (34.6, per-batch reuse)
  const size_t MB = 1024ull*1024ull;
  char* ws = (char*)d_ws;
  u16*   Xh    = (u16*)(ws + 0);
  float* NVacc = (float*)(ws + 0);
  u16*   H     = (u16*)(ws + 0);
  u16*   Xl    = (u16*)(ws + 16*MB);
  u16*   QKl   = (u16*)(ws + 32*MB);
  u16*   QKh   = (u16*)(ws + 64*MB);
  u16*   Vt    = (u16*)(ws + 96*MB);
  u16*   NV    = (u16*)(ws + 112*MB);
  u16*   Wqkh  = (u16*)(ws + 128*MB);
  u16*   Wqkl  = (u16*)(ws + 129*MB);
  u16*   Wvt   = (u16*)(ws + 130*MB);
  u16*   W1t   = (u16*)(ws + 131*MB);
  u16*   W2t   = (u16*)(ws + 133*MB);
  float* Sp    = (float*)(ws + 135*MB);

  dim3 tb(32, 8);

  // 1. split-cast X
  k_split_cast<<<Mrows*Cch/4/256, 256, 0, stream>>>(X, Xh, Xl, Mrows*Cch);

  // 2. weight transposes (Wq/Wk split, Wv/W1/W2 plain)
  k_transpose_split<<<dim3(16,16), tb, 0, stream>>>(Wq, Wqkh,           Wqkl,           512, 512);
  k_transpose_split<<<dim3(16,16), tb, 0, stream>>>(Wk, Wqkh + 512*512, Wqkl + 512*512, 512, 512);
  k_transpose_f32_bf16<<<dim3(16,16), tb, 0, stream>>>(Wv, Wvt, 512, 512);
  k_transpose_f32_bf16<<<dim3(64,16), tb, 0, stream>>>(W1, W1t, 2048, 512);
  k_transpose_f32_bf16<<<dim3(16,64), tb, 0, stream>>>(W2, W2t, 512, 2048);

  // 3. QK projection (split); V projection (plain, writes transposed Vt)
  k_qk_split<<<dim3(128, 8), 256, 0, stream>>>(Xh, Xl, Wqkh, Wqkl, QKh, QKl);
  k_gemm<4><<<dim3(128, 4), 256, 0, stream>>>(Xh, Wvt, Vt, nullptr, Cch, Cch);

  // 4. attention, batch-serial: score GEMM -> softmax -> split-K PV -> finalize
  for(int b = 0; b < Bb; b++){
    k_zero4<<<Tt*Cch/4/256, 256, 0, stream>>>(NVacc, Tt*Cch);
    k_score<<<dim3(32, 32), 256, 0, stream>>>(QKh + (size_t)b*Tt*1024,
                                              QKl + (size_t)b*Tt*1024, Sp);
    k_softmax<<<1024, 256, 0, stream>>>(Sp);
    k_pv<<<dim3(4, 32, 4), 256, 0, stream>>>((const u16*)Sp, Vt + (size_t)b*Cch*Tt, NVacc);
    k_nv_final<<<Tt*Cch/4/256, 256, 0, stream>>>(NVacc, NV + (size_t)b*Tt*Cch, Tt*Cch);
  }

  // 5. FFN
  k_gemm<1><<<dim3(128, 16), 256, 0, stream>>>(NV, W1t, H,   b1, Cch,  DFFd);
  k_gemm<2><<<dim3(128, 4),  256, 0, stream>>>(H,  W2t, out, b2, DFFd, Cch);
}

// Round 6
// 535.059 us; speedup vs baseline: 5.3003x; 1.1741x over previous
//
#include <hip/hip_runtime.h>
#include <stdint.h>

typedef __attribute__((ext_vector_type(8))) short bf16x8;
typedef __attribute__((ext_vector_type(8))) _Float16 f16x8;
typedef __attribute__((ext_vector_type(4))) float f32x4;
typedef __attribute__((ext_vector_type(4))) unsigned short us4;
typedef unsigned short u16;

#define DEVI static __device__ __forceinline__

#define Bb 4
#define Tt 4096
#define Cch 512
#define DFFd 2048
#define Mrows (Bb*Tt)

DEVI u16 f2bf(float f){
  union{float f;unsigned u;} v; v.f = f;
  unsigned r = v.u + 0x7FFFu + ((v.u >> 16) & 1u);
  return (u16)(r >> 16);
}
DEVI float bf2f(u16 h){
  union{unsigned u;float f;} v; v.u = (unsigned)h << 16; return v.f;
}
DEVI u16 f2h(float f){
  union{_Float16 h; u16 u;} v; v.h = (_Float16)f; return v.u;
}
// packed-triangular pane offset (f32 elements): sum_{j<q}(j+1)*128*128
DEVI size_t PANE(int q){ return (size_t)8192 * (size_t)(q*(q+1)); }

DEVI void gload16(const void* g, void* l){
  __builtin_amdgcn_global_load_lds((const __attribute__((address_space(1))) unsigned int*)g,
                                   (__attribute__((address_space(3))) unsigned int*)l, 16, 0, 0);
}

// ---------------- split cast f32 -> (hi, lo) bf16 ----------------
__global__ void k_split_cast(const float* __restrict__ in, u16* __restrict__ hi,
                             u16* __restrict__ lo, int n){
  int i = (blockIdx.x * blockDim.x + threadIdx.x) * 4;
  if(i < n){
    float4 f = *(const float4*)(in + i);
    us4 h, l;
    h.x = f2bf(f.x); l.x = f2bf(f.x - bf2f(h.x));
    h.y = f2bf(f.y); l.y = f2bf(f.y - bf2f(h.y));
    h.z = f2bf(f.z); l.z = f2bf(f.z - bf2f(h.z));
    h.w = f2bf(f.w); l.w = f2bf(f.w - bf2f(h.w));
    *(us4*)(hi + i) = h; *(us4*)(lo + i) = l;
  }
}

// ------------- transpose-cast f32 -> bf16 (plain) -------------
__global__ void k_transpose_f32_bf16(const float* __restrict__ in, u16* __restrict__ out,
                                     int inStride, int outStride){
  __shared__ float tile[32][33];
  int c0 = blockIdx.x * 32, r0 = blockIdx.y * 32;
  int tx = threadIdx.x, ty = threadIdx.y; // (32,8)
  #pragma unroll
  for(int j = 0; j < 4; j++)
    tile[ty + 8*j][tx] = in[(size_t)(r0 + ty + 8*j) * inStride + c0 + tx];
  __syncthreads();
  #pragma unroll
  for(int j = 0; j < 4; j++)
    out[(size_t)(c0 + ty + 8*j) * outStride + r0 + tx] = f2bf(tile[tx][ty + 8*j]);
}

// ------------- transpose-cast f32 -> (hi,lo) bf16 -------------
__global__ void k_transpose_split(const float* __restrict__ in, u16* __restrict__ oh,
                                  u16* __restrict__ ol, int inStride, int outStride){
  __shared__ float tile[32][33];
  int c0 = blockIdx.x * 32, r0 = blockIdx.y * 32;
  int tx = threadIdx.x, ty = threadIdx.y;
  #pragma unroll
  for(int j = 0; j < 4; j++)
    tile[ty + 8*j][tx] = in[(size_t)(r0 + ty + 8*j) * inStride + c0 + tx];
  __syncthreads();
  #pragma unroll
  for(int j = 0; j < 4; j++){
    float x = tile[tx][ty + 8*j];
    u16 h = f2bf(x);
    size_t o = (size_t)(c0 + ty + 8*j) * outStride + r0 + tx;
    oh[o] = h; ol[o] = f2bf(x - bf2f(h));
  }
}

// ---------------- split-precision GEMM core (bf16 hi/lo, 3 MFMA) ----------------
DEVI void core_split(const u16* __restrict__ Ah, const u16* __restrict__ Al,
                     const u16* __restrict__ Bh, const u16* __restrict__ Bl,
                     int lda, int ldb, int K,
                     u16* Ash, u16* Asl, u16* Bsh, u16* Bsl,
                     f32x4 (&acc)[4][4]){
  const int t = threadIdx.x;
  const int lane = t & 63, w = t >> 6;
  const int l15 = lane & 15, l4 = lane >> 4;
  const int wr = (w >> 1) * 64, wc = (w & 1) * 64;
  for(int kt = 0; kt < K; kt += 32){
    __syncthreads();
    #pragma unroll
    for(int i = 0; i < 2; i++){
      int row = i*64 + (t >> 2);
      int ce  = (t & 3) * 8;
      size_t ao = (size_t)row * lda + kt + ce;
      size_t bo = (size_t)row * ldb + kt + ce;
      gload16(Ah + ao, (char*)Ash + i*4096 + t*16);
      gload16(Al + ao, (char*)Asl + i*4096 + t*16);
      gload16(Bh + bo, (char*)Bsh + i*4096 + t*16);
      gload16(Bl + bo, (char*)Bsl + i*4096 + t*16);
    }
    __syncthreads();
    bf16x8 ah[4], al[4], bh[4], bl[4];
    #pragma unroll
    for(int mi = 0; mi < 4; mi++){
      ah[mi] = *(const bf16x8*)((const char*)Ash + (wr + mi*16 + l15)*64 + l4*16);
      al[mi] = *(const bf16x8*)((const char*)Asl + (wr + mi*16 + l15)*64 + l4*16);
    }
    #pragma unroll
    for(int ni = 0; ni < 4; ni++){
      bh[ni] = *(const bf16x8*)((const char*)Bsh + (wc + ni*16 + l15)*64 + l4*16);
      bl[ni] = *(const bf16x8*)((const char*)Bsl + (wc + ni*16 + l15)*64 + l4*16);
    }
    #pragma unroll
    for(int mi = 0; mi < 4; mi++)
      #pragma unroll
      for(int ni = 0; ni < 4; ni++){
        acc[mi][ni] = __builtin_amdgcn_mfma_f32_16x16x32_bf16(ah[mi], bh[ni], acc[mi][ni], 0, 0, 0);
        acc[mi][ni] = __builtin_amdgcn_mfma_f32_16x16x32_bf16(ah[mi], bl[ni], acc[mi][ni], 0, 0, 0);
        acc[mi][ni] = __builtin_amdgcn_mfma_f32_16x16x32_bf16(al[mi], bh[ni], acc[mi][ni], 0, 0, 0);
      }
  }
}

// ---------------- QK projection, split precision, single f16 output [M][1024] ----------------
__global__ __launch_bounds__(256) void k_qk_split(const u16* __restrict__ Xh, const u16* __restrict__ Xl,
                                                  const u16* __restrict__ Wh, const u16* __restrict__ Wl,
                                                  u16* __restrict__ QK){
  __shared__ u16 Ash[4096], Asl[4096], Bsh[4096], Bsl[4096];
  const int bm = blockIdx.x * 128, bn = blockIdx.y * 128;
  f32x4 acc[4][4] = {};
  core_split(Xh + (size_t)bm*512, Xl + (size_t)bm*512,
             Wh + (size_t)bn*512, Wl + (size_t)bn*512,
             512, 512, 512, Ash, Asl, Bsh, Bsl, acc);
  const int t = threadIdx.x, lane = t & 63, w = t >> 6;
  const int l15 = lane & 15, l4 = lane >> 4;
  const int wr = (w >> 1) * 64, wc = (w & 1) * 64;
  #pragma unroll
  for(int mi = 0; mi < 4; mi++)
    #pragma unroll
    for(int ni = 0; ni < 4; ni++){
      int col = bn + wc + ni*16 + l15;
      #pragma unroll
      for(int r = 0; r < 4; r++){
        int row = bm + wr + mi*16 + l4*4 + r;
        QK[(size_t)row * 1024 + col] = f2h(acc[mi][ni][r]);
      }
    }
}

// ---------------- f16 GEMM core (single MFMA) ----------------
DEVI void core_f16(const u16* __restrict__ A, const u16* __restrict__ B,
                   int lda, int ldb, int K, u16* As, u16* Bs, f32x4 (&acc)[4][4]){
  const int t = threadIdx.x;
  const int lane = t & 63, w = t >> 6;
  const int l15 = lane & 15, l4 = lane >> 4;
  const int wr = (w >> 1) * 64, wc = (w & 1) * 64;
  for(int kt = 0; kt < K; kt += 32){
    __syncthreads();
    #pragma unroll
    for(int i = 0; i < 2; i++){
      int row = i*64 + (t >> 2);
      int ce  = (t & 3) * 8;
      gload16(A + (size_t)row * lda + kt + ce, (char*)As + i*4096 + t*16);
      gload16(B + (size_t)row * ldb + kt + ce, (char*)Bs + i*4096 + t*16);
    }
    __syncthreads();
    f16x8 af[4], bfr[4];
    #pragma unroll
    for(int mi = 0; mi < 4; mi++)
      af[mi] = *(const f16x8*)((const char*)As + (wr + mi*16 + l15)*64 + l4*16);
    #pragma unroll
    for(int ni = 0; ni < 4; ni++)
      bfr[ni] = *(const f16x8*)((const char*)Bs + (wc + ni*16 + l15)*64 + l4*16);
    #pragma unroll
    for(int mi = 0; mi < 4; mi++)
      #pragma unroll
      for(int ni = 0; ni < 4; ni++)
        acc[mi][ni] = __builtin_amdgcn_mfma_f32_16x16x32_f16(af[mi], bfr[ni], acc[mi][ni], 0, 0, 0);
  }
}

// ---------------- causal score GEMM (one batch), f16, packed f32 out ----------------
__global__ __launch_bounds__(256) void k_score(const u16* __restrict__ QKb,
                                               float* __restrict__ Sp){
  const int kt = blockIdx.x, qt = blockIdx.y;
  if(kt > qt) return;
  __shared__ u16 As[4096], Bs[4096];
  const u16* A = QKb + (size_t)(qt*128) * 1024;        // q rows
  const u16* B = QKb + (size_t)(kt*128) * 1024 + 512;  // k rows
  f32x4 acc[4][4] = {};
  core_f16(A, B, 1024, 1024, 512, As, Bs, acc);
  const int t = threadIdx.x, lane = t & 63, w = t >> 6;
  const int l15 = lane & 15, l4 = lane >> 4;
  const int wr = (w >> 1) * 64, wc = (w & 1) * 64;
  const int ldc = (qt + 1) * 128;
  float* C = Sp + PANE(qt) + (size_t)kt*128;
  const bool diag = (kt == qt);
  #pragma unroll
  for(int mi = 0; mi < 4; mi++)
    #pragma unroll
    for(int ni = 0; ni < 4; ni++){
      int cl = wc + ni*16 + l15;
      #pragma unroll
      for(int r = 0; r < 4; r++){
        int rl = wr + mi*16 + l4*4 + r;
        float v = acc[mi][ni][r];
        if(diag && cl > rl) v = -__builtin_inff();
        C[(size_t)rl * ldc + cl] = v;
      }
    }
}

// ---------------- softmax (one batch): wave per row, f32 -> packed bf16 in row's own bytes ----------------
__global__ __launch_bounds__(256) void k_softmax(float* __restrict__ Sp){
  const int w = threadIdx.x >> 6, lane = threadIdx.x & 63;
  const int r = blockIdx.x * 4 + w;           // 0..4095
  const int qt = r >> 7;
  const int L = (qt + 1) * 128, nc = qt + 1;  // chunks of 128 f32 (float2/lane)
  const size_t base = PANE(qt) + (size_t)(r & 127) * L;
  const float2* rp = (const float2*)(Sp + base);
  float2 v[32];
  float mx = -__builtin_inff();
  #pragma unroll
  for(int c = 0; c < 32; c++) if(c < nc){
    v[c] = rp[c*64 + lane];
    mx = fmaxf(mx, fmaxf(v[c].x, v[c].y));
  }
  #pragma unroll
  for(int s = 1; s < 64; s <<= 1) mx = fmaxf(mx, __shfl_xor(mx, s));
  float sm = 0.f;
  #pragma unroll
  for(int c = 0; c < 32; c++) if(c < nc){
    v[c].x = __expf(v[c].x - mx);
    v[c].y = __expf(v[c].y - mx);
    sm += v[c].x + v[c].y;
  }
  #pragma unroll
  for(int s = 1; s < 64; s <<= 1) sm += __shfl_xor(sm, s);
  const float inv = 1.f / sm;
  // bf16 P packed at the START of this row's own f32 region (no cross-row overlap)
  ushort2* wp = (ushort2*)((u16*)Sp + 2*base);
  #pragma unroll
  for(int c = 0; c < 32; c++) if(c < nc){
    ushort2 o; o.x = f2bf(v[c].x * inv); o.y = f2bf(v[c].y * inv);
    wp[c*64 + lane] = o;
  }
}

// ---------------- plain bf16 GEMM core ----------------
DEVI void core_plain(const u16* __restrict__ A, const u16* __restrict__ B,
                     int lda, int ldb, int K, u16* As, u16* Bs, f32x4 (&acc)[4][4]){
  const int t = threadIdx.x;
  const int lane = t & 63, w = t >> 6;
  const int l15 = lane & 15, l4 = lane >> 4;
  const int wr = (w >> 1) * 64, wc = (w & 1) * 64;
  for(int kt = 0; kt < K; kt += 32){
    __syncthreads();
    #pragma unroll
    for(int i = 0; i < 2; i++){
      int row = i*64 + (t >> 2);
      int ce  = (t & 3) * 8;
      gload16(A + (size_t)row * lda + kt + ce, (char*)As + i*4096 + t*16);
      gload16(B + (size_t)row * ldb + kt + ce, (char*)Bs + i*4096 + t*16);
    }
    __syncthreads();
    bf16x8 af[4], bfr[4];
    #pragma unroll
    for(int mi = 0; mi < 4; mi++)
      af[mi] = *(const bf16x8*)((const char*)As + (wr + mi*16 + l15)*64 + l4*16);
    #pragma unroll
    for(int ni = 0; ni < 4; ni++)
      bfr[ni] = *(const bf16x8*)((const char*)Bs + (wc + ni*16 + l15)*64 + l4*16);
    #pragma unroll
    for(int mi = 0; mi < 4; mi++)
      #pragma unroll
      for(int ni = 0; ni < 4; ni++)
        acc[mi][ni] = __builtin_amdgcn_mfma_f32_16x16x32_bf16(af[mi], bfr[ni], acc[mi][ni], 0, 0, 0);
  }
}

// ---------------- PV split-K GEMM (one batch): atomicAdd into f32 accumulator ----------------
__global__ __launch_bounds__(256) void k_pv(const u16* __restrict__ Pp, const u16* __restrict__ Vtb,
                                            float* __restrict__ NVacc){
  const int nc = blockIdx.x, qt = blockIdx.y, kc = blockIdx.z;
  const int L = (qt + 1) * 128;
  const int k0 = kc * 1024;
  if(k0 >= L) return;
  const int kLen = (L - k0) < 1024 ? (L - k0) : 1024;
  __shared__ u16 As[4096], Bs[4096];
  const u16* A = Pp + 2*PANE(qt) + k0;                 // P rows: u16 stride 2L, data in low L
  const u16* B = Vtb + (size_t)(nc*128) * Tt + k0;     // Vt rows = V columns
  f32x4 acc[4][4] = {};
  core_plain(A, B, 2*L, Tt, kLen, As, Bs, acc);
  const int t = threadIdx.x, lane = t & 63, w = t >> 6;
  const int l15 = lane & 15, l4 = lane >> 4;
  const int wr = (w >> 1) * 64, wc = (w & 1) * 64;
  float* Cb = NVacc + (size_t)(qt*128) * Cch + nc*128;
  #pragma unroll
  for(int mi = 0; mi < 4; mi++)
    #pragma unroll
    for(int ni = 0; ni < 4; ni++){
      int cl = wc + ni*16 + l15;
      #pragma unroll
      for(int r = 0; r < 4; r++){
        int rl = wr + mi*16 + l4*4 + r;
        atomicAdd(&Cb[(size_t)rl * Cch + cl], acc[mi][ni][r]);
      }
    }
}

// ---------------- plain GEMM with epilogues ----------------
// EPI: 1 = +bias, relu, store bf16 ; 2 = +bias, store f32 ; 4 = store bf16 transposed per batch (Vt)
template<int EPI>
__global__ __launch_bounds__(256) void k_gemm(const u16* __restrict__ A,
                                              const u16* __restrict__ Bt,
                                              void* __restrict__ Cp,
                                              const float* __restrict__ bias,
                                              int K, int ldc){
  __shared__ u16 As[4096], Bs[4096];
  const int bm = blockIdx.x * 128, bn = blockIdx.y * 128;
  f32x4 acc[4][4] = {};
  core_plain(A + (size_t)bm*K, Bt + (size_t)bn*K, K, K, K, As, Bs, acc);
  const int t = threadIdx.x, lane = t & 63, w = t >> 6;
  const int l15 = lane & 15, l4 = lane >> 4;
  const int wr = (w >> 1) * 64, wc = (w & 1) * 64;
  #pragma unroll
  for(int mi = 0; mi < 4; mi++)
    #pragma unroll
    for(int ni = 0; ni < 4; ni++){
      int col = bn + wc + ni*16 + l15;
      float bv = (EPI == 1 || EPI == 2) ? bias[col] : 0.f;
      #pragma unroll
      for(int r = 0; r < 4; r++){
        int row = bm + wr + mi*16 + l4*4 + r;
        float v = acc[mi][ni][r] + bv;
        if(EPI == 1){ v = v > 0.f ? v : 0.f; ((u16*)Cp)[(size_t)row * ldc + col] = f2bf(v); }
        else if(EPI == 2){ ((float*)Cp)[(size_t)row * ldc + col] = v; }
        else {
          // Vt[b][col][t] = V[row][col]
          int b = row >> 12, tq = row & 4095;
          ((u16*)Cp)[((size_t)b * Cch + col) * Tt + tq] = f2bf(v);
        }
      }
    }
}

// ---------------- small utility kernels ----------------
__global__ void k_zero4(float* __restrict__ p, int n){
  int i = (blockIdx.x * blockDim.x + threadIdx.x) * 4;
  if(i < n) *(f32x4*)(p + i) = (f32x4){0.f,0.f,0.f,0.f};
}
__global__ void k_nv_final(const float* __restrict__ acc, u16* __restrict__ nv, int n){
  int i = (blockIdx.x * blockDim.x + threadIdx.x) * 4;
  if(i < n){
    f32x4 v = *(const f32x4*)(acc + i);
    us4 o; o.x = f2bf(v[0]); o.y = f2bf(v[1]); o.z = f2bf(v[2]); o.w = f2bf(v[3]);
    *(us4*)(nv + i) = o;
  }
}

// ---------------- launch ----------------
extern "C" void kernel_launch(void* const* d_in, const int* in_sizes, int n_in,
                              void* d_out, int out_size, void* d_ws, size_t ws_size,
                              hipStream_t stream){
  (void)in_sizes; (void)n_in; (void)out_size; (void)ws_size;
  const float* X  = (const float*)d_in[0];
  const float* Wq = (const float*)d_in[1];
  const float* Wk = (const float*)d_in[2];
  const float* Wv = (const float*)d_in[3];
  const float* W1 = (const float*)d_in[4];
  const float* b1 = (const float*)d_in[5];
  const float* W2 = (const float*)d_in[6];
  const float* b2 = (const float*)d_in[7];
  float* out = (float*)d_out;

  // workspace layout (byte offsets), peak ~169.6 MB
  // 0   Xh(16) -> NVacc(32, all batches, after projections) -> H(64, FFN)
  // 16  Xl(16)
  // 64  QK f16 (32)
  // 96  Vt(16)
  // 112 NV(16)
  // 128 weights (7)
  // 135 S pane buffer (34.6, per-batch reuse)
  const size_t MB = 1024ull*1024ull;
  char* ws = (char*)d_ws;
  u16*   Xh    = (u16*)(ws + 0);
  float* NVacc = (float*)(ws + 0);
  u16*   H     = (u16*)(ws + 0);
  u16*   Xl    = (u16*)(ws + 16*MB);
  u16*   QK    = (u16*)(ws + 64*MB);
  u16*   Vt    = (u16*)(ws + 96*MB);
  u16*   NV    = (u16*)(ws + 112*MB);
  u16*   Wqkh  = (u16*)(ws + 128*MB);
  u16*   Wqkl  = (u16*)(ws + 129*MB);
  u16*   Wvt   = (u16*)(ws + 130*MB);
  u16*   W1t   = (u16*)(ws + 131*MB);
  u16*   W2t   = (u16*)(ws + 133*MB);
  float* Sp    = (float*)(ws + 135*MB);

  dim3 tb(32, 8);

  // 1. split-cast X
  k_split_cast<<<Mrows*Cch/4/256, 256, 0, stream>>>(X, Xh, Xl, Mrows*Cch);

  // 2. weight transposes (Wq/Wk split, Wv/W1/W2 plain)
  k_transpose_split<<<dim3(16,16), tb, 0, stream>>>(Wq, Wqkh,           Wqkl,           512, 512);
  k_transpose_split<<<dim3(16,16), tb, 0, stream>>>(Wk, Wqkh + 512*512, Wqkl + 512*512, 512, 512);
  k_transpose_f32_bf16<<<dim3(16,16), tb, 0, stream>>>(Wv, Wvt, 512, 512);
  k_transpose_f32_bf16<<<dim3(64,16), tb, 0, stream>>>(W1, W1t, 2048, 512);
  k_transpose_f32_bf16<<<dim3(16,64), tb, 0, stream>>>(W2, W2t, 512, 2048);

  // 3. QK projection (split-bf16 compute, f16 store); V projection (plain, writes transposed Vt)
  k_qk_split<<<dim3(128, 8), 256, 0, stream>>>(Xh, Xl, Wqkh, Wqkl, QK);
  k_gemm<4><<<dim3(128, 4), 256, 0, stream>>>(Xh, Wvt, Vt, nullptr, Cch, Cch);

  // 4. attention: zero all-batch accumulator once (Xh/Xl dead now), per-batch score/softmax/pv
  k_zero4<<<Mrows*Cch/4/256, 256, 0, stream>>>(NVacc, Mrows*Cch);
  for(int b = 0; b < Bb; b++){
    k_score<<<dim3(32, 32), 256, 0, stream>>>(QK + (size_t)b*Tt*1024, Sp);
    k_softmax<<<1024, 256, 0, stream>>>(Sp);
    k_pv<<<dim3(4, 32, 4), 256, 0, stream>>>((const u16*)Sp, Vt + (size_t)b*Cch*Tt,
                                             NVacc + (size_t)b*Tt*Cch);
  }
  k_nv_final<<<Mrows*Cch/4/256, 256, 0, stream>>>(NVacc, NV, Mrows*Cch);

  // 5. FFN
  k_gemm<1><<<dim3(128, 16), 256, 0, stream>>>(NV, W1t, H,   b1, Cch,  DFFd);
  k_gemm<2><<<dim3(128, 4),  256, 0, stream>>>(H,  W2t, out, b2, DFFd, Cch);
}